// Round 5
// baseline (783.734 us; speedup 1.0000x reference)
//
#include <hip/hip_runtime.h>

#define TSTEPS 12
#define NNODES 50000
#define DIN 32
#define HDIM 128
#define DECS 7
#define MTILE 96
#define NRT 6                                   // row-tiles of 16
#define NTILES ((NNODES + MTILE - 1) / MTILE)   // 521 -> 2.03 blocks/CU

#define HS 140     // halves/row: 280B = 70 dw, bank step 6 -> b128 reads 2-way (free, r3-measured)
#define XS 36      // halves/row per timestep of x tile (step 18 -> 2-way free)
#define XSLOTS 6   // rolling x buffer depth (reuse distance 6 > pipeline distance 1)

typedef _Float16 half_t;
typedef _Float16 half8 __attribute__((ext_vector_type(8)));
typedef _Float16 half4_ __attribute__((ext_vector_type(4)));
typedef float float4_ __attribute__((ext_vector_type(4)));

// ---------------- workspace layout (halves then floats) ----------------
// halves: [0] WihE 65536 | [65536] WhhE | [131072] WihD | [196608] WhhD |
//         [262144] encW 4096 | [266240] fc1 8192
// floats at byte 548864: b_e[512], b_d[512]
#define WS_FLOAT_OFF 548864

// Fast activations: v_exp_f32 + v_rcp_f32 (~1 ulp each) — r4-verified absmax 9.8e-4.
#if __has_builtin(__builtin_amdgcn_exp2f)
#define EXP2F __builtin_amdgcn_exp2f
#else
#define EXP2F exp2f
#endif
#if __has_builtin(__builtin_amdgcn_rcpf)
#define RCPF __builtin_amdgcn_rcpf
#else
#define RCPF(x) (1.0f / (x))
#endif

__device__ __forceinline__ float sigmoidf_(float x) {
    return RCPF(1.0f + EXP2F(-1.44269504f * x));
}
__device__ __forceinline__ float tanhf_(float x) {
    return fmaf(2.0f, RCPF(1.0f + EXP2F(-2.88539008f * x)), -1.0f);
}

// Pack fp32 [R,C] row-major into fragment-major fp16 (B-operand layout):
// dst[((ct*KB+kb)*64 + lane)*8 + j] = src[ct*16 + (lane&15)][kb*32 + (lane>>4)*8 + j]
__global__ void pack_weights_k(const float* __restrict__ src, half_t* __restrict__ dst,
                               int C, int KB, int total) {
    int tid = blockIdx.x * blockDim.x + threadIdx.x;
    if (tid >= total) return;
    int j    = tid & 7;
    int lane = (tid >> 3) & 63;
    int rest = tid >> 9;
    int kb   = rest % KB;
    int ct   = rest / KB;
    int row  = ct * 16 + (lane & 15);
    int col  = kb * 32 + ((lane >> 4) << 3) + j;
    dst[tid] = (half_t)src[row * C + col];
}

__global__ void prep_bias_k(const float* __restrict__ bih_e, const float* __restrict__ bhh_e,
                            const float* __restrict__ bih_d, const float* __restrict__ bhh_d,
                            float* __restrict__ be, float* __restrict__ bd) {
    int tid = blockIdx.x * blockDim.x + threadIdx.x;
    if (tid < 512) {
        be[tid] = bih_e[tid] + bhh_e[tid];
        bd[tid] = bih_d[tid] + bhh_d[tid];
    }
}

// Stage one timestep of x (96 rows x 32 cols, fp32->fp16) into xa slot t%XSLOTS.
__device__ __forceinline__ void stage_x(const float* __restrict__ x, half_t* __restrict__ xa,
                                        int t, int n0, int tid) {
    if (tid < MTILE * 4) {
        int row = tid >> 2;
        int c0  = (tid & 3) * 8;
        int n   = n0 + row;
        float4_ a0 = {0.f, 0.f, 0.f, 0.f}, a1 = {0.f, 0.f, 0.f, 0.f};
        if (n < NNODES) {
            const float* p = x + ((size_t)t * NNODES + n) * DIN + c0;
            a0 = *(const float4_*)p;
            a1 = *(const float4_*)(p + 4);
        }
        half8 hv;
        hv[0] = (half_t)a0[0]; hv[1] = (half_t)a0[1]; hv[2] = (half_t)a0[2]; hv[3] = (half_t)a0[3];
        hv[4] = (half_t)a1[0]; hv[5] = (half_t)a1[1]; hv[6] = (half_t)a1[2]; hv[7] = (half_t)a1[3];
        *(half8*)(xa + ((t % XSLOTS) * MTILE + row) * XS + c0) = hv;
    }
}

// Encoder LSTM step: z = e@Wih^T + h@Whh^T + b. Wave w owns z cols [16w,16w+16)/gate.
__device__ __forceinline__ void lstm_step_enc(
    const half_t* __restrict__ eA, const half_t* __restrict__ hA, half_t* __restrict__ hOut,
    const half8 (&wfi)[4][4], const half8 (&wfh)[4][4],
    const float bR[4], float cS[NRT][4],
    int w, int q, int l15) {
#pragma unroll
    for (int rt = 0; rt < NRT; ++rt) {
        float4_ acc[4];
#pragma unroll
        for (int g = 0; g < 4; ++g) {
            float b = bR[g];
            acc[g][0] = b; acc[g][1] = b; acc[g][2] = b; acc[g][3] = b;
        }
#pragma unroll
        for (int kb = 0; kb < 4; ++kb) {
            half8 ae = *(const half8*)(eA + (rt * 16 + l15) * HS + kb * 32 + q * 8);
            half8 ah = *(const half8*)(hA + (rt * 16 + l15) * HS + kb * 32 + q * 8);
#pragma unroll
            for (int g = 0; g < 4; ++g) {
                acc[g] = __builtin_amdgcn_mfma_f32_16x16x32_f16(ae, wfi[g][kb], acc[g], 0, 0, 0);
                acc[g] = __builtin_amdgcn_mfma_f32_16x16x32_f16(ah, wfh[g][kb], acc[g], 0, 0, 0);
            }
        }
#pragma unroll
        for (int r = 0; r < 4; ++r) {
            float iv = sigmoidf_(acc[0][r]);
            float fv = sigmoidf_(acc[1][r]);
            float gv = tanhf_(acc[2][r]);
            float ov = sigmoidf_(acc[3][r]);
            float c  = fv * cS[rt][r] + iv * gv;
            cS[rt][r] = c;
            float h = ov * tanhf_(c);
            hOut[(rt * 16 + q * 4 + r) * HS + w * 16 + l15] = (half_t)h;
        }
    }
}

// Decoder LSTM step: z = zx + h@Whh^T, zx precomputed (d_in term is step-invariant).
// Half the MFMAs / half the A-reads of the encoder step.
__device__ __forceinline__ void lstm_step_dec(
    const half_t* __restrict__ hA, half_t* __restrict__ hOut,
    const half8 (&wfh)[4][4], const half4_ (&zx)[4][NRT],
    float cS[NRT][4], int w, int q, int l15) {
#pragma unroll
    for (int rt = 0; rt < NRT; ++rt) {
        float4_ acc[4];
#pragma unroll
        for (int g = 0; g < 4; ++g) {
#pragma unroll
            for (int r = 0; r < 4; ++r) acc[g][r] = (float)zx[g][rt][r];
        }
#pragma unroll
        for (int kb = 0; kb < 4; ++kb) {
            half8 ah = *(const half8*)(hA + (rt * 16 + l15) * HS + kb * 32 + q * 8);
#pragma unroll
            for (int g = 0; g < 4; ++g)
                acc[g] = __builtin_amdgcn_mfma_f32_16x16x32_f16(ah, wfh[g][kb], acc[g], 0, 0, 0);
        }
#pragma unroll
        for (int r = 0; r < 4; ++r) {
            float iv = sigmoidf_(acc[0][r]);
            float fv = sigmoidf_(acc[1][r]);
            float gv = tanhf_(acc[2][r]);
            float ov = sigmoidf_(acc[3][r]);
            float c  = fv * cS[rt][r] + iv * gv;
            cS[rt][r] = c;
            float h = ov * tanhf_(c);
            hOut[(rt * 16 + q * 4 + r) * HS + w * 16 + l15] = (half_t)h;
        }
    }
}

// e_t = relu(x_t @ encW^T + enc_b); wave w computes e cols [16w,16w+16)
__device__ __forceinline__ void enc_proj(
    const half_t* __restrict__ xa, half_t* __restrict__ eOut,
    half8 encWf, float benc, int t, int w, int q, int l15) {
    const half_t* xs = xa + (t % XSLOTS) * MTILE * XS;
#pragma unroll
    for (int rt = 0; rt < NRT; ++rt) {
        half8 af = *(const half8*)(xs + (rt * 16 + l15) * XS + q * 8);
        float4_ a;
        a[0] = benc; a[1] = benc; a[2] = benc; a[3] = benc;
        a = __builtin_amdgcn_mfma_f32_16x16x32_f16(af, encWf, a, 0, 0, 0);
#pragma unroll
        for (int r = 0; r < 4; ++r) {
            float v = a[r];
            v = v > 0.f ? v : 0.f;
            eOut[(rt * 16 + q * 4 + r) * HS + w * 16 + l15] = (half_t)v;
        }
    }
}

__global__ __launch_bounds__(512, 2) void seq2seq_main_k(
    const float* __restrict__ x,
    const float* __restrict__ enc_b,
    const float* __restrict__ fc1_b,
    const float* __restrict__ fc2_W,
    const float* __restrict__ fc2_b,
    const half_t* __restrict__ wsh,
    const float* __restrict__ be,
    const float* __restrict__ bd,
    float* __restrict__ out) {
    __shared__ __align__(16) half_t xa[XSLOTS * MTILE * XS];   // 41472 B
    __shared__ __align__(16) half_t e_lds[2][MTILE * HS];      // 53760 B
    __shared__ __align__(16) half_t h_lds[2][MTILE * HS];      // 53760 B
    __shared__ float pred_lds[4][MTILE];                       // 1536 B -> 150.5 KB total

    const int tid  = threadIdx.x;
    const int lane = tid & 63;
    const int w    = tid >> 6;        // wave 0..7
    const int q    = lane >> 4;
    const int l15  = lane & 15;
    const int n0   = blockIdx.x * MTILE;

    const half_t* WihE  = wsh;
    const half_t* WhhE  = wsh + 65536;
    const half_t* WihD  = wsh + 131072;
    const half_t* WhhD  = wsh + 196608;
    const half_t* encWp = wsh + 262144;
    const half_t* fc1p  = wsh + 266240;

    // per-wave biases: z col = g*128 + w*16 + l15
    float beR[4], bdR[4];
#pragma unroll
    for (int g = 0; g < 4; ++g) {
        int col = g * 128 + w * 16 + l15;
        beR[g] = be[col];
        bdR[g] = bd[col];
    }
    float benc = enc_b[w * 16 + l15];

    // prime the rolling x buffer with t = 0..5
#pragma unroll
    for (int t = 0; t < XSLOTS; ++t) stage_x(x, xa, t, n0, tid);

    // zero initial h
    for (int i = tid; i < MTILE * HS; i += 512) h_lds[0][i] = (half_t)0.0f;

    float c_reg[NRT][4];
#pragma unroll
    for (int rt = 0; rt < NRT; ++rt)
#pragma unroll
        for (int r = 0; r < 4; ++r) c_reg[rt][r] = 0.0f;

    // ---- encoder weights into registers (per-wave slice: 128 VGPRs) ----
    half8 wfi[4][4], wfh[4][4];
#pragma unroll
    for (int g = 0; g < 4; ++g)
#pragma unroll
        for (int kb = 0; kb < 4; ++kb) {
            int ct = g * 8 + w;
            wfi[g][kb] = *(const half8*)(WihE + ((size_t)(ct * 4 + kb) * 64 + lane) * 8);
            wfh[g][kb] = *(const half8*)(WhhE + ((size_t)(ct * 4 + kb) * 64 + lane) * 8);
        }
    half8 encWf = *(const half8*)(encWp + (size_t)w * 512 + lane * 8);

    __syncthreads();  // xa(0..5) + h0 ready

    enc_proj(xa, e_lds[0], encWf, benc, 0, w, q, l15);
    __syncthreads();  // e0 ready

    int cur = 0;
    // ================= encoder: one barrier per step =================
    for (int t = 0; t < TSTEPS; ++t) {
        lstm_step_enc(e_lds[t & 1], h_lds[cur], h_lds[cur ^ 1], wfi, wfh, beR, c_reg, w, q, l15);
        if (t + XSLOTS < TSTEPS)
            stage_x(x, xa, t + XSLOTS, n0, tid);   // slot t%6: last read by proj(t) in iter t-1
        if (t + 1 < TSTEPS)
            enc_proj(xa, e_lds[(t & 1) ^ 1], encWf, benc, t + 1, w, q, l15);
        __syncthreads();
        cur ^= 1;
    }

    // ---- decoder: reload weights; precompute zx = d_in@WihD^T + b_d (step-invariant) ----
#pragma unroll
    for (int g = 0; g < 4; ++g)
#pragma unroll
        for (int kb = 0; kb < 4; ++kb) {
            int ct = g * 8 + w;
            wfi[g][kb] = *(const half8*)(WihD + ((size_t)(ct * 4 + kb) * 64 + lane) * 8);
            wfh[g][kb] = *(const half8*)(WhhD + ((size_t)(ct * 4 + kb) * 64 + lane) * 8);
        }
    half8 fc1f[4];
#pragma unroll
    for (int kb = 0; kb < 4; ++kb)
        fc1f[kb] = *(const half8*)(fc1p + ((size_t)((w & 3) * 4 + kb) * 64 + lane) * 8);
    float bf1 = fc1_b[(w & 3) * 16 + l15];
    float wf2 = fc2_W[(w & 3) * 16 + l15];
    float bf2 = fc2_b[0];
    const int rtH = (w >> 2) * 3;

    // zx is wave-private (wave computes and consumes its own cols) -> registers, fp16.
    half4_ zx[4][NRT];
    {
        const half_t* dA = h_lds[cur];   // final encoder h = d_in
#pragma unroll
        for (int rt = 0; rt < NRT; ++rt) {
            float4_ acc[4];
#pragma unroll
            for (int g = 0; g < 4; ++g) {
                float b = bdR[g];
                acc[g][0] = b; acc[g][1] = b; acc[g][2] = b; acc[g][3] = b;
            }
#pragma unroll
            for (int kb = 0; kb < 4; ++kb) {
                half8 af = *(const half8*)(dA + (rt * 16 + l15) * HS + kb * 32 + q * 8);
#pragma unroll
                for (int g = 0; g < 4; ++g)
                    acc[g] = __builtin_amdgcn_mfma_f32_16x16x32_f16(af, wfi[g][kb], acc[g], 0, 0, 0);
            }
#pragma unroll
            for (int g = 0; g < 4; ++g)
#pragma unroll
                for (int r = 0; r < 4; ++r) zx[g][rt][r] = (half_t)acc[g][r];
        }
    }

    // ================= decoder =================
    for (int s = 0; s < DECS; ++s) {
        lstm_step_dec(h_lds[cur], h_lds[cur ^ 1], wfh, zx, c_reg, w, q, l15);
        cur ^= 1;
        __syncthreads();  // new h ready
        // head: o64 = relu(h @ fc1^T + b1); pred = o64 @ fc2^T + b2
#pragma unroll
        for (int rp = 0; rp < 3; ++rp) {
            int rt = rtH + rp;
            float4_ hacc;
            hacc[0] = bf1; hacc[1] = bf1; hacc[2] = bf1; hacc[3] = bf1;
#pragma unroll
            for (int kb = 0; kb < 4; ++kb) {
                half8 af = *(const half8*)(h_lds[cur] + (rt * 16 + l15) * HS + kb * 32 + q * 8);
                hacc = __builtin_amdgcn_mfma_f32_16x16x32_f16(af, fc1f[kb], hacc, 0, 0, 0);
            }
#pragma unroll
            for (int r = 0; r < 4; ++r) {
                float v = hacc[r];
                v = v > 0.f ? v : 0.f;
                v *= wf2;
                v += __shfl_xor(v, 1, 64);
                v += __shfl_xor(v, 2, 64);
                v += __shfl_xor(v, 4, 64);
                v += __shfl_xor(v, 8, 64);
                if (l15 == 0) pred_lds[w & 3][rt * 16 + q * 4 + r] = v;
            }
        }
        __syncthreads();
        if (tid < MTILE) {
            float sum = pred_lds[0][tid] + pred_lds[1][tid] + pred_lds[2][tid] + pred_lds[3][tid] + bf2;
            int n = n0 + tid;
            if (n < NNODES) out[(size_t)n * DECS + s] = sum;
        }
        // pred_lds(s+1) writes are ordered behind the next lstm step's barrier
    }
}

extern "C" void kernel_launch(void* const* d_in, const int* in_sizes, int n_in,
                              void* d_out, int out_size, void* d_ws, size_t ws_size,
                              hipStream_t stream) {
    (void)in_sizes; (void)n_in; (void)out_size; (void)ws_size;
    const float* x     = (const float*)d_in[0];
    const float* enc_W = (const float*)d_in[1];
    const float* enc_b = (const float*)d_in[2];
    const float* Wih_e = (const float*)d_in[3];
    const float* Whh_e = (const float*)d_in[4];
    const float* bih_e = (const float*)d_in[5];
    const float* bhh_e = (const float*)d_in[6];
    const float* Wih_d = (const float*)d_in[7];
    const float* Whh_d = (const float*)d_in[8];
    const float* bih_d = (const float*)d_in[9];
    const float* bhh_d = (const float*)d_in[10];
    const float* fc1_W = (const float*)d_in[11];
    const float* fc1_b = (const float*)d_in[12];
    const float* fc2_W = (const float*)d_in[13];
    const float* fc2_b = (const float*)d_in[14];

    half_t* wsh = (half_t*)d_ws;
    float*  be  = (float*)((char*)d_ws + WS_FLOAT_OFF);
    float*  bd  = be + 512;

    pack_weights_k<<<256, 256, 0, stream>>>(Wih_e, wsh + 0,      128, 4, 65536);
    pack_weights_k<<<256, 256, 0, stream>>>(Whh_e, wsh + 65536,  128, 4, 65536);
    pack_weights_k<<<256, 256, 0, stream>>>(Wih_d, wsh + 131072, 128, 4, 65536);
    pack_weights_k<<<256, 256, 0, stream>>>(Whh_d, wsh + 196608, 128, 4, 65536);
    pack_weights_k<<<16,  256, 0, stream>>>(enc_W, wsh + 262144, 32,  1, 4096);
    pack_weights_k<<<32,  256, 0, stream>>>(fc1_W, wsh + 266240, 128, 4, 8192);
    prep_bias_k<<<2, 256, 0, stream>>>(bih_e, bhh_e, bih_d, bhh_d, be, bd);

    seq2seq_main_k<<<NTILES, 512, 0, stream>>>(x, enc_b, fc1_b, fc2_W, fc2_b,
                                               wsh, be, bd, (float*)d_out);
}

// Round 6
// 655.841 us; speedup vs baseline: 1.1950x; 1.1950x over previous
//
#include <hip/hip_runtime.h>

#define TSTEPS 12
#define NNODES 50000
#define DIN 32
#define HDIM 128
#define DECS 7
#define MTILE 112
#define NRT 7                                   // row-tiles of 16
#define NTILES ((NNODES + MTILE - 1) / MTILE)   // 447 -> every CU runs <=2 block-rounds (no odd tail)

#define HS 140     // halves/row: r5-measured ZERO bank conflicts at this stride
#define XS 36      // halves/row per timestep of x tile
#define XSLOTS 2   // rolling x buffer: stage t+2 during step t

typedef _Float16 half_t;
typedef _Float16 half8 __attribute__((ext_vector_type(8)));
typedef _Float16 half4_ __attribute__((ext_vector_type(4)));
typedef float float4_ __attribute__((ext_vector_type(4)));

// ---------------- workspace layout (halves then floats) ----------------
#define WS_FLOAT_OFF 548864

#if __has_builtin(__builtin_amdgcn_exp2f)
#define EXP2F __builtin_amdgcn_exp2f
#else
#define EXP2F exp2f
#endif
#if __has_builtin(__builtin_amdgcn_rcpf)
#define RCPF __builtin_amdgcn_rcpf
#else
#define RCPF(x) (1.0f / (x))
#endif

#define K_LOG2E 1.44269504f

__device__ __forceinline__ float sigmoidf_(float x) {
    return RCPF(1.0f + EXP2F(-K_LOG2E * x));
}
// sigma(a) * tanh(b) with ONE rcp: (e^{2b}-1) / [(1+e^{-a})(e^{2b}+1)]
__device__ __forceinline__ float sig_mul_tanh(float a, float b) {
    float ea  = EXP2F(-K_LOG2E * a);
    float tb  = EXP2F(2.0f * K_LOG2E * b);
    float tp1 = tb + 1.0f;
    return (tb - 1.0f) * RCPF(fmaf(ea, tp1, tp1));
}

// Pack fp32 [R,C] row-major into fragment-major fp16 (B-operand layout):
// dst[((ct*KB+kb)*64 + lane)*8 + j] = src[ct*16 + (lane&15)][kb*32 + (lane>>4)*8 + j]
__global__ void pack_weights_k(const float* __restrict__ src, half_t* __restrict__ dst,
                               int C, int KB, int total) {
    int tid = blockIdx.x * blockDim.x + threadIdx.x;
    if (tid >= total) return;
    int j    = tid & 7;
    int lane = (tid >> 3) & 63;
    int rest = tid >> 9;
    int kb   = rest % KB;
    int ct   = rest / KB;
    int row  = ct * 16 + (lane & 15);
    int col  = kb * 32 + ((lane >> 4) << 3) + j;
    dst[tid] = (half_t)src[row * C + col];
}

__global__ void prep_bias_k(const float* __restrict__ bih_e, const float* __restrict__ bhh_e,
                            const float* __restrict__ bih_d, const float* __restrict__ bhh_d,
                            float* __restrict__ be, float* __restrict__ bd) {
    int tid = blockIdx.x * blockDim.x + threadIdx.x;
    if (tid < 512) {
        be[tid] = bih_e[tid] + bhh_e[tid];
        bd[tid] = bih_d[tid] + bhh_d[tid];
    }
}

// Stage one timestep of x (112 rows x 32 cols, fp32->fp16) into xa slot t&1.
__device__ __forceinline__ void stage_x(const float* __restrict__ x, half_t* __restrict__ xa,
                                        int t, int n0, int tid) {
    if (tid < MTILE * 4) {
        int row = tid >> 2;
        int c0  = (tid & 3) * 8;
        int n   = n0 + row;
        float4_ a0 = {0.f, 0.f, 0.f, 0.f}, a1 = {0.f, 0.f, 0.f, 0.f};
        if (n < NNODES) {
            const float* p = x + ((size_t)t * NNODES + n) * DIN + c0;
            a0 = *(const float4_*)p;
            a1 = *(const float4_*)(p + 4);
        }
        half8 hv;
        hv[0] = (half_t)a0[0]; hv[1] = (half_t)a0[1]; hv[2] = (half_t)a0[2]; hv[3] = (half_t)a0[3];
        hv[4] = (half_t)a1[0]; hv[5] = (half_t)a1[1]; hv[6] = (half_t)a1[2]; hv[7] = (half_t)a1[3];
        *(half8*)(xa + ((t & 1) * MTILE + row) * XS + c0) = hv;
    }
}

// Gate nonlinearity + cell update for one acc-tile element set (C-layout write of h).
__device__ __forceinline__ void cell_update(
    const float4_ acc[4], float cS[4], half_t* __restrict__ hOut,
    int rt, int w, int q, int l15) {
#pragma unroll
    for (int r = 0; r < 4; ++r) {
        float sf = sigmoidf_(acc[1][r]);
        float ig = sig_mul_tanh(acc[0][r], acc[2][r]);   // sigma(i)*tanh(g)
        float c  = fmaf(sf, cS[r], ig);
        cS[r] = c;
        float h = sig_mul_tanh(acc[3][r], c);            // sigma(o)*tanh(c)
        hOut[(rt * 16 + q * 4 + r) * HS + w * 16 + l15] = (half_t)h;
    }
}

// Encoder LSTM step: z = e@Wih^T + h@Whh^T + b. Wave w owns z cols [16w,16w+16)/gate.
__device__ __forceinline__ void lstm_step_enc(
    const half_t* __restrict__ eA, const half_t* __restrict__ hA, half_t* __restrict__ hOut,
    const half8 (&wfi)[4][4], const half8 (&wfh)[4][4],
    const float bR[4], float cS[NRT][4],
    int w, int q, int l15) {
#pragma unroll
    for (int rt = 0; rt < NRT; ++rt) {
        float4_ acc[4];
#pragma unroll
        for (int g = 0; g < 4; ++g) {
            float b = bR[g];
            acc[g][0] = b; acc[g][1] = b; acc[g][2] = b; acc[g][3] = b;
        }
#pragma unroll
        for (int kb = 0; kb < 4; ++kb) {
            half8 ae = *(const half8*)(eA + (rt * 16 + l15) * HS + kb * 32 + q * 8);
            half8 ah = *(const half8*)(hA + (rt * 16 + l15) * HS + kb * 32 + q * 8);
#pragma unroll
            for (int g = 0; g < 4; ++g) {
                acc[g] = __builtin_amdgcn_mfma_f32_16x16x32_f16(ae, wfi[g][kb], acc[g], 0, 0, 0);
                acc[g] = __builtin_amdgcn_mfma_f32_16x16x32_f16(ah, wfh[g][kb], acc[g], 0, 0, 0);
            }
        }
        cell_update(acc, cS[rt], hOut, rt, w, q, l15);
    }
}

// Decoder LSTM step: z = zx + h@Whh^T (zx = d_in@Wih^T + b precomputed, step-invariant).
__device__ __forceinline__ void lstm_step_dec(
    const half_t* __restrict__ hA, half_t* __restrict__ hOut,
    const half8 (&wfh)[4][4], const half4_ (&zx)[4][NRT],
    float cS[NRT][4], int w, int q, int l15) {
#pragma unroll
    for (int rt = 0; rt < NRT; ++rt) {
        float4_ acc[4];
#pragma unroll
        for (int g = 0; g < 4; ++g) {
#pragma unroll
            for (int r = 0; r < 4; ++r) acc[g][r] = (float)zx[g][rt][r];
        }
#pragma unroll
        for (int kb = 0; kb < 4; ++kb) {
            half8 ah = *(const half8*)(hA + (rt * 16 + l15) * HS + kb * 32 + q * 8);
#pragma unroll
            for (int g = 0; g < 4; ++g)
                acc[g] = __builtin_amdgcn_mfma_f32_16x16x32_f16(ah, wfh[g][kb], acc[g], 0, 0, 0);
        }
        cell_update(acc, cS[rt], hOut, rt, w, q, l15);
    }
}

// e_t = relu(x_t @ encW^T + enc_b); wave w computes e cols [16w,16w+16)
__device__ __forceinline__ void enc_proj(
    const half_t* __restrict__ xa, half_t* __restrict__ eOut,
    half8 encWf, float benc, int t, int w, int q, int l15) {
    const half_t* xs = xa + (t & 1) * MTILE * XS;
#pragma unroll
    for (int rt = 0; rt < NRT; ++rt) {
        half8 af = *(const half8*)(xs + (rt * 16 + l15) * XS + q * 8);
        float4_ a;
        a[0] = benc; a[1] = benc; a[2] = benc; a[3] = benc;
        a = __builtin_amdgcn_mfma_f32_16x16x32_f16(af, encWf, a, 0, 0, 0);
#pragma unroll
        for (int r = 0; r < 4; ++r) {
            float v = a[r];
            v = v > 0.f ? v : 0.f;
            eOut[(rt * 16 + q * 4 + r) * HS + w * 16 + l15] = (half_t)v;
        }
    }
}

__global__ __launch_bounds__(512, 2) void seq2seq_main_k(
    const float* __restrict__ x,
    const float* __restrict__ enc_b,
    const float* __restrict__ fc1_b,
    const float* __restrict__ fc2_W,
    const float* __restrict__ fc2_b,
    const half_t* __restrict__ wsh,
    const float* __restrict__ be,
    const float* __restrict__ bd,
    float* __restrict__ out) {
    __shared__ __align__(16) half_t xa[XSLOTS * MTILE * XS];   // 16128 B
    __shared__ __align__(16) half_t e_lds[2][MTILE * HS];      // 62720 B
    __shared__ __align__(16) half_t h_lds[2][MTILE * HS];      // 62720 B
    __shared__ float pred_lds[4][MTILE];                       // 1792 B  -> 140 KB total

    const int tid  = threadIdx.x;
    const int lane = tid & 63;
    const int w    = tid >> 6;        // wave 0..7
    const int q    = lane >> 4;
    const int l15  = lane & 15;
    const int n0   = blockIdx.x * MTILE;

    const half_t* WihE  = wsh;
    const half_t* WhhE  = wsh + 65536;
    const half_t* WihD  = wsh + 131072;
    const half_t* WhhD  = wsh + 196608;
    const half_t* encWp = wsh + 262144;
    const half_t* fc1p  = wsh + 266240;

    // per-wave biases: z col = g*128 + w*16 + l15
    float beR[4], bdR[4];
#pragma unroll
    for (int g = 0; g < 4; ++g) {
        int col = g * 128 + w * 16 + l15;
        beR[g] = be[col];
        bdR[g] = bd[col];
    }
    float benc = enc_b[w * 16 + l15];

    // prime rolling x buffer with t=0,1
    stage_x(x, xa, 0, n0, tid);
    stage_x(x, xa, 1, n0, tid);

    // zero initial h
    for (int i = tid; i < MTILE * HS; i += 512) h_lds[0][i] = (half_t)0.0f;

    float c_reg[NRT][4];
#pragma unroll
    for (int rt = 0; rt < NRT; ++rt)
#pragma unroll
        for (int r = 0; r < 4; ++r) c_reg[rt][r] = 0.0f;

    // ---- encoder weights into registers (per-wave slice: 128 VGPRs) ----
    half8 wfi[4][4], wfh[4][4];
#pragma unroll
    for (int g = 0; g < 4; ++g)
#pragma unroll
        for (int kb = 0; kb < 4; ++kb) {
            int ct = g * 8 + w;
            wfi[g][kb] = *(const half8*)(WihE + ((size_t)(ct * 4 + kb) * 64 + lane) * 8);
            wfh[g][kb] = *(const half8*)(WhhE + ((size_t)(ct * 4 + kb) * 64 + lane) * 8);
        }
    half8 encWf = *(const half8*)(encWp + (size_t)w * 512 + lane * 8);

    __syncthreads();  // xa(0,1) + h0 ready

    enc_proj(xa, e_lds[0], encWf, benc, 0, w, q, l15);
    __syncthreads();  // e0 ready

    int cur = 0;
    // ================= encoder: one barrier per step =================
    for (int t = 0; t < TSTEPS; ++t) {
        lstm_step_enc(e_lds[t & 1], h_lds[cur], h_lds[cur ^ 1], wfi, wfh, beR, c_reg, w, q, l15);
        if (t + 2 < TSTEPS)
            stage_x(x, xa, t + 2, n0, tid);   // writes slot t&1 (its proj(t) read finished in step t-1)
        if (t + 1 < TSTEPS)
            enc_proj(xa, e_lds[(t + 1) & 1], encWf, benc, t + 1, w, q, l15);
        __syncthreads();
        cur ^= 1;
    }

    // ---- decoder: zx = d_in@WihD^T + b_d, computed BEFORE loading WhhD (spill-safe) ----
#pragma unroll
    for (int g = 0; g < 4; ++g)
#pragma unroll
        for (int kb = 0; kb < 4; ++kb) {
            int ct = g * 8 + w;
            wfi[g][kb] = *(const half8*)(WihD + ((size_t)(ct * 4 + kb) * 64 + lane) * 8);
        }
    half4_ zx[4][NRT];
    {
        const half_t* dA = h_lds[cur];   // final encoder h = d_in (fixed across decoder steps)
#pragma unroll
        for (int rt = 0; rt < NRT; ++rt) {
            float4_ acc[4];
#pragma unroll
            for (int g = 0; g < 4; ++g) {
                float b = bdR[g];
                acc[g][0] = b; acc[g][1] = b; acc[g][2] = b; acc[g][3] = b;
            }
#pragma unroll
            for (int kb = 0; kb < 4; ++kb) {
                half8 af = *(const half8*)(dA + (rt * 16 + l15) * HS + kb * 32 + q * 8);
#pragma unroll
                for (int g = 0; g < 4; ++g)
                    acc[g] = __builtin_amdgcn_mfma_f32_16x16x32_f16(af, wfi[g][kb], acc[g], 0, 0, 0);
            }
#pragma unroll
            for (int g = 0; g < 4; ++g)
#pragma unroll
                for (int r = 0; r < 4; ++r) zx[g][rt][r] = (half_t)acc[g][r];
        }
    }
    // now wfi is dead -> load decoder recurrent weights + head params
#pragma unroll
    for (int g = 0; g < 4; ++g)
#pragma unroll
        for (int kb = 0; kb < 4; ++kb) {
            int ct = g * 8 + w;
            wfh[g][kb] = *(const half8*)(WhhD + ((size_t)(ct * 4 + kb) * 64 + lane) * 8);
        }
    half8 fc1f[4];
#pragma unroll
    for (int kb = 0; kb < 4; ++kb)
        fc1f[kb] = *(const half8*)(fc1p + ((size_t)((w & 3) * 4 + kb) * 64 + lane) * 8);
    float bf1 = fc1_b[(w & 3) * 16 + l15];
    float wf2 = fc2_W[(w & 3) * 16 + l15];
    float bf2 = fc2_b[0];
    const int rt0  = (w >> 2) * 4;            // head row-tiles: waves 0-3 -> rt 0..3, waves 4-7 -> rt 4..6
    const int rtN  = (w >> 2) ? 3 : 4;

    // ================= decoder =================
    for (int s = 0; s < DECS; ++s) {
        lstm_step_dec(h_lds[cur], h_lds[cur ^ 1], wfh, zx, c_reg, w, q, l15);
        cur ^= 1;
        __syncthreads();  // new h ready
        // head: o64 = relu(h @ fc1^T + b1); pred = o64 @ fc2^T + b2
#pragma unroll
        for (int rp = 0; rp < 4; ++rp) {
            if (rp < rtN) {
                int rt = rt0 + rp;
                float4_ hacc;
                hacc[0] = bf1; hacc[1] = bf1; hacc[2] = bf1; hacc[3] = bf1;
#pragma unroll
                for (int kb = 0; kb < 4; ++kb) {
                    half8 af = *(const half8*)(h_lds[cur] + (rt * 16 + l15) * HS + kb * 32 + q * 8);
                    hacc = __builtin_amdgcn_mfma_f32_16x16x32_f16(af, fc1f[kb], hacc, 0, 0, 0);
                }
#pragma unroll
                for (int r = 0; r < 4; ++r) {
                    float v = hacc[r];
                    v = v > 0.f ? v : 0.f;
                    v *= wf2;
                    v += __shfl_xor(v, 1, 64);
                    v += __shfl_xor(v, 2, 64);
                    v += __shfl_xor(v, 4, 64);
                    v += __shfl_xor(v, 8, 64);
                    if (l15 == 0) pred_lds[w & 3][rt * 16 + q * 4 + r] = v;
                }
            }
        }
        __syncthreads();
        if (tid < MTILE) {
            float sum = pred_lds[0][tid] + pred_lds[1][tid] + pred_lds[2][tid] + pred_lds[3][tid] + bf2;
            int n = n0 + tid;
            if (n < NNODES) out[(size_t)n * DECS + s] = sum;
        }
        // pred_lds(s+1) writes are ordered behind the next lstm step's barrier
    }
}

extern "C" void kernel_launch(void* const* d_in, const int* in_sizes, int n_in,
                              void* d_out, int out_size, void* d_ws, size_t ws_size,
                              hipStream_t stream) {
    (void)in_sizes; (void)n_in; (void)out_size; (void)ws_size;
    const float* x     = (const float*)d_in[0];
    const float* enc_W = (const float*)d_in[1];
    const float* enc_b = (const float*)d_in[2];
    const float* Wih_e = (const float*)d_in[3];
    const float* Whh_e = (const float*)d_in[4];
    const float* bih_e = (const float*)d_in[5];
    const float* bhh_e = (const float*)d_in[6];
    const float* Wih_d = (const float*)d_in[7];
    const float* Whh_d = (const float*)d_in[8];
    const float* bih_d = (const float*)d_in[9];
    const float* bhh_d = (const float*)d_in[10];
    const float* fc1_W = (const float*)d_in[11];
    const float* fc1_b = (const float*)d_in[12];
    const float* fc2_W = (const float*)d_in[13];
    const float* fc2_b = (const float*)d_in[14];

    half_t* wsh = (half_t*)d_ws;
    float*  be  = (float*)((char*)d_ws + WS_FLOAT_OFF);
    float*  bd  = be + 512;

    pack_weights_k<<<256, 256, 0, stream>>>(Wih_e, wsh + 0,      128, 4, 65536);
    pack_weights_k<<<256, 256, 0, stream>>>(Whh_e, wsh + 65536,  128, 4, 65536);
    pack_weights_k<<<256, 256, 0, stream>>>(Wih_d, wsh + 131072, 128, 4, 65536);
    pack_weights_k<<<256, 256, 0, stream>>>(Whh_d, wsh + 196608, 128, 4, 65536);
    pack_weights_k<<<16,  256, 0, stream>>>(enc_W, wsh + 262144, 32,  1, 4096);
    pack_weights_k<<<32,  256, 0, stream>>>(fc1_W, wsh + 266240, 128, 4, 8192);
    prep_bias_k<<<2, 256, 0, stream>>>(bih_e, bhh_e, bih_d, bhh_d, be, bd);

    seq2seq_main_k<<<NTILES, 512, 0, stream>>>(x, enc_b, fc1_b, fc2_W, fc2_b,
                                               wsh, be, bd, (float*)d_out);
}